// Round 2
// baseline (87.792 us; speedup 1.0000x reference)
//
#include <hip/hip_runtime.h>

// Problem constants (from reference)
#define NUM_DAYS    4096
#define NUM_ATTR    512
#define MB_WIN      128
#define HID         500
#define NUM_BATCHES (NUM_DAYS - MB_WIN)        // 3968
#define NUM_Y       (NUM_BATCHES + MB_WIN - 1) // 4095 distinct day indices
#define OUT_ELEMS   (NUM_BATCHES * MB_WIN)     // 507904

// Fused-kernel tiling: each block owns WPB consecutive windows.
#define WPB         16                          // windows per block
#define N_BLOCKS    (NUM_BATCHES / WPB)         // 248
#define DAYS_PB     (WPB + MB_WIN - 1)          // 143 distinct days per block
#define OUT4_PB     (WPB * MB_WIN / 4)          // 512 float4 per block

// ---------------------------------------------------------------------------
// Kernel 1: fold the MLP:  v[a] = sum_h W1[a,h]*W2[h],  c = b1.W2 + b2
// One wave per output; lane-strided row reads are coalesced.
// ---------------------------------------------------------------------------
__global__ __launch_bounds__(64) void k_fold_weights(
    const float* __restrict__ W1, const float* __restrict__ b1,
    const float* __restrict__ W2, const float* __restrict__ b2,
    float* __restrict__ v, float* __restrict__ c) {
    const int b    = blockIdx.x;
    const int lane = threadIdx.x;  // 0..63
    float acc = 0.f;
    if (b < NUM_ATTR) {
        const float* row = W1 + (size_t)b * HID;
        for (int h = lane; h < HID; h += 64) acc += row[h] * W2[h];
    } else {
        for (int h = lane; h < HID; h += 64) acc += b1[h] * W2[h];
    }
    #pragma unroll
    for (int off = 32; off >= 1; off >>= 1) acc += __shfl_down(acc, off, 64);
    if (lane == 0) {
        if (b < NUM_ATTR) v[b] = acc;
        else              *c   = acc + b2[0];
    }
}

// ---------------------------------------------------------------------------
// Kernel 2 (fused): per block of 16 windows:
//   phase A: y_lds[t] = x[w0+t,:] . v + c   for t in [0,143)  (wave-per-day,
//            lane-split 512-dot, coalesced float4 x loads, v in LDS/regs)
//   phase B: out[w0*128 + o] = y_lds[(o>>7) + (o&127)]  as float4 stores
// ---------------------------------------------------------------------------
__global__ __launch_bounds__(256) void k_fused_out(
    const float* __restrict__ x, const float* __restrict__ v,
    const float* __restrict__ c, float* __restrict__ out) {
    __shared__ float v_lds[NUM_ATTR];
    __shared__ float y_lds[DAYS_PB];
    __shared__ float c_s;

    const int tid  = threadIdx.x;
    const int wave = tid >> 6;
    const int lane = tid & 63;
    const int w0   = blockIdx.x * WPB;

    // preload v (and c) into LDS
    v_lds[tid]       = v[tid];
    v_lds[tid + 256] = v[tid + 256];
    if (tid == 0) c_s = *c;
    __syncthreads();

    // phase A: wave-per-day
    const float4* v4 = (const float4*)v_lds;
    const float4  v0 = v4[lane];
    const float4  v1 = v4[lane + 64];
    const float4* x4 = (const float4*)x;
    for (int t = wave; t < DAYS_PB; t += 4) {
        const int d = w0 + t;
        float4 a0 = x4[(size_t)d * 128 + lane];
        float4 a1 = x4[(size_t)d * 128 + 64 + lane];
        float acc = a0.x * v0.x + a0.y * v0.y + a0.z * v0.z + a0.w * v0.w
                  + a1.x * v1.x + a1.y * v1.y + a1.z * v1.z + a1.w * v1.w;
        #pragma unroll
        for (int off = 32; off >= 1; off >>= 1) acc += __shfl_down(acc, off, 64);
        if (lane == 0) y_lds[t] = acc + c_s;
    }
    __syncthreads();

    // phase B: coalesced float4 stores of the block's 2048 outputs
    float4* out4 = (float4*)out;
    #pragma unroll
    for (int r = 0; r < OUT4_PB / 256; ++r) {
        const int j    = tid + r * 256;        // float4 index within block
        const int base = j << 2;               // local out offset
        const int wl   = base >> 7;
        const int m    = base & 127;
        const int dl   = wl + m;
        float4 rr;
        rr.x = y_lds[dl];
        rr.y = y_lds[dl + 1];
        rr.z = y_lds[dl + 2];
        rr.w = y_lds[dl + 3];
        out4[(size_t)blockIdx.x * OUT4_PB + j] = rr;
    }
}

extern "C" void kernel_launch(void* const* d_in, const int* in_sizes, int n_in,
                              void* d_out, int out_size, void* d_ws, size_t ws_size,
                              hipStream_t stream) {
    const float* x  = (const float*)d_in[0];  // [4096, 512]
    const float* W1 = (const float*)d_in[1];  // [512, 500]
    const float* b1 = (const float*)d_in[2];  // [500]
    const float* W2 = (const float*)d_in[3];  // [500, 1]
    const float* b2 = (const float*)d_in[4];  // [1]
    float* out = (float*)d_out;               // [507904]

    float* ws = (float*)d_ws;
    float* v  = ws;          // 512 floats
    float* c  = ws + 512;    // 1 float

    k_fold_weights<<<NUM_ATTR + 1, 64, 0, stream>>>(W1, b1, W2, b2, v, c);
    k_fused_out<<<N_BLOCKS, 256, 0, stream>>>(x, v, c, out);
}

// Round 4
// 73.771 us; speedup vs baseline: 1.1901x; 1.1901x over previous
//
#include <hip/hip_runtime.h>

// Problem constants (from reference)
#define NUM_DAYS    4096
#define NUM_ATTR    512
#define MB_WIN      128
#define HID         500
#define NUM_BATCHES (NUM_DAYS - MB_WIN)        // 3968
#define NUM_Y       (NUM_BATCHES + MB_WIN - 1) // 4095 distinct day indices
#define OUT_ELEMS   (NUM_BATCHES * MB_WIN)     // 507904

// ---------------------------------------------------------------------------
// Kernel 1: fold the MLP:  v[a] = sum_h W1[a,h]*W2[h],  c = b1.W2 + b2
// One wave per output; lane-strided row reads are coalesced.
// ---------------------------------------------------------------------------
__global__ __launch_bounds__(64) void k_fold_weights(
    const float* __restrict__ W1, const float* __restrict__ b1,
    const float* __restrict__ W2, const float* __restrict__ b2,
    float* __restrict__ v, float* __restrict__ c) {
    const int b    = blockIdx.x;
    const int lane = threadIdx.x;  // 0..63
    float acc = 0.f;
    if (b < NUM_ATTR) {
        const float* row = W1 + (size_t)b * HID;
        for (int h = lane; h < HID; h += 64) acc += row[h] * W2[h];
    } else {
        for (int h = lane; h < HID; h += 64) acc += b1[h] * W2[h];
    }
    #pragma unroll
    for (int off = 32; off >= 1; off >>= 1) acc += __shfl_down(acc, off, 64);
    if (lane == 0) {
        if (b < NUM_ATTR) v[b] = acc;
        else              *c   = acc + b2[0];
    }
}

// ---------------------------------------------------------------------------
// Kernel 2 (fused dot + value-scatter): one wave per day d.
//   y = x[d,:].v + c   (coalesced float4 loads, butterfly reduce -> all lanes)
//   store y to every output that references day d:
//     out[w*128 + m] with w = d - m, for m in {lane, lane+64}, 0<=w<3968.
// Each out element is written exactly once across the grid.
// ---------------------------------------------------------------------------
__global__ __launch_bounds__(64) void k_dot_scatter(
    const float* __restrict__ x, const float* __restrict__ v,
    const float* __restrict__ c, float* __restrict__ out) {
    const int d    = blockIdx.x;   // 0..NUM_Y-1
    const int lane = threadIdx.x;  // 0..63
    const float4* xr = (const float4*)(x + (size_t)d * NUM_ATTR);
    const float4* vr = (const float4*)v;
    float4 a0 = xr[lane];
    float4 a1 = xr[lane + 64];
    float4 v0 = vr[lane];
    float4 v1 = vr[lane + 64];
    float acc = a0.x * v0.x + a0.y * v0.y + a0.z * v0.z + a0.w * v0.w
              + a1.x * v1.x + a1.y * v1.y + a1.z * v1.z + a1.w * v1.w;
    #pragma unroll
    for (int off = 32; off >= 1; off >>= 1) acc += __shfl_xor(acc, off, 64);
    const float yv = acc + *c;

    const int m0 = lane,      w0 = d - m0;
    const int m1 = lane + 64, w1 = d - m1;
    if (w0 >= 0 && w0 < NUM_BATCHES) out[(size_t)w0 * MB_WIN + m0] = yv;
    if (w1 >= 0 && w1 < NUM_BATCHES) out[(size_t)w1 * MB_WIN + m1] = yv;
}

extern "C" void kernel_launch(void* const* d_in, const int* in_sizes, int n_in,
                              void* d_out, int out_size, void* d_ws, size_t ws_size,
                              hipStream_t stream) {
    const float* x  = (const float*)d_in[0];  // [4096, 512]
    const float* W1 = (const float*)d_in[1];  // [512, 500]
    const float* b1 = (const float*)d_in[2];  // [500]
    const float* W2 = (const float*)d_in[3];  // [500, 1]
    const float* b2 = (const float*)d_in[4];  // [1]
    float* out = (float*)d_out;               // [507904]

    float* ws = (float*)d_ws;
    float* v  = ws;          // 512 floats
    float* c  = ws + 512;    // 1 float

    k_fold_weights<<<NUM_ATTR + 1, 64, 0, stream>>>(W1, b1, W2, b2, v, c);
    k_dot_scatter<<<NUM_Y, 64, 0, stream>>>(x, v, c, out);
}